// Round 2
// baseline (293.204 us; speedup 1.0000x reference)
//
#include <hip/hip_runtime.h>
#include <math.h>

// Problem constants: B=8, C=64, H=W=64, O=64, K=3, KK=9, HW=4096
// ws layout (floats):
//   [0, 36864)        Wt[(c*9+k)*64 + o]   = weight[o][c][k]      (transposed)
//   [36864, 67968)    OWt[(ci*9+t)*27+oc]  = om_weight[oc][ci][t] (transposed)
//   [131072, +3538944) omp[q][b][27][4096]  om-conv partials, q = ci-quarter
#define WT_OFF   0
#define OWT_OFF  36864
#define OMP_OFF  131072

__global__ __launch_bounds__(256) void prep_kernel(
    const float* __restrict__ weight, const float* __restrict__ om_weight,
    float* __restrict__ ws)
{
    int idx = blockIdx.x * 256 + threadIdx.x;
    if (idx < 36864) {
        int o = idx & 63;
        int ck = idx >> 6;
        int c = ck / 9;
        int k = ck - c * 9;
        ws[WT_OFF + idx] = weight[(o * 64 + c) * 9 + k];
    } else if (idx < 67968) {
        int e = idx - 36864;
        int oc = e % 27;
        int r = e / 27;
        int ci = r / 9;
        int t = r - ci * 9;
        ws[OWT_OFF + e] = om_weight[(oc * 128 + ci) * 9 + t];
    }
}

// om = conv2d(concat(feat, deg), om_weight), computed as 4 partial sums over
// input-channel quarters. One thread per (quarter, pixel); lane = w.
// Weights are wave-uniform -> scalar loads. 27 fp32 accumulators per thread.
__global__ __launch_bounds__(256) void omconv_kernel(
    const float* __restrict__ feat, const float* __restrict__ deg,
    const float* __restrict__ ws_c, float* __restrict__ omp)
{
    const int q   = blockIdx.x >> 7;                          // 0..3 (scalar)
    const int pix = (blockIdx.x & 127) * 256 + threadIdx.x;   // 0..32767
    const int b = pix >> 12;
    const int h = (pix >> 6) & 63;
    const int w = pix & 63;
    const float* src = (q < 2) ? feat : deg;
    const int c0 = (q & 1) * 32;       // local channel start in chosen tensor
    const float* OWt = ws_c + OWT_OFF;

    float acc[27];
#pragma unroll
    for (int i = 0; i < 27; i++) acc[i] = 0.f;

    for (int i = 0; i < 32; i++) {
        const int c  = c0 + i;
        const int cg = q * 32 + i;     // concat channel (scalar)
        const float* sp = src + (b * 64 + c) * 4096;
        float v[9];
#pragma unroll
        for (int t = 0; t < 9; t++) {
            int ky = t / 3, kx = t - (t / 3) * 3;
            int y = h - 1 + ky, x = w - 1 + kx;
            bool ok = (y >= 0) & (y < 64) & (x >= 0) & (x < 64);
            v[t] = ok ? sp[y * 64 + x] : 0.f;
        }
        const float* wp = OWt + cg * 243;   // uniform -> s_load_dwordx16
#pragma unroll
        for (int t = 0; t < 9; t++)
#pragma unroll
            for (int oc = 0; oc < 27; oc++)
                acc[oc] = fmaf(v[t], wp[t * 27 + oc], acc[oc]);
    }

    float* dst = omp + ((q * 8 + b) * 27) * 4096 + h * 64 + w;
#pragma unroll
    for (int oc = 0; oc < 27; oc++) dst[oc * 4096] = acc[oc];
}

// Deformable conv. One block per (b, h) row; lane = w; 4 waves split the 64
// input channels 16 each. Per lane: precompute per-k bilinear weights (mask &
// validity folded in) + independently-clamped tap offsets, then per c:
// 36 gathers -> 9 sampled values -> 576 FMAs against wave-uniform (scalar)
// weights into 64 fp32 accumulators. 4-wave LDS reduction at the end.
__global__ __launch_bounds__(256) void deform_kernel(
    const float* __restrict__ feat, const float* __restrict__ om_bias,
    const float* __restrict__ ws_c, float* __restrict__ out)
{
    __shared__ float red[4096];
    const int b = blockIdx.x >> 6;
    const int h = blockIdx.x & 63;
    const int w = threadIdx.x & 63;
    const int wv = __builtin_amdgcn_readfirstlane(threadIdx.x >> 6); // 0..3
    const float* Wt  = ws_c + WT_OFF;
    const float* omp = ws_c + OMP_OFF;
    const int hw = h * 64 + w;

    float W00[9], W01[9], W10[9], W11[9];
    int   A00[9], A01[9], A10[9], A11[9];
#pragma unroll
    for (int k = 0; k < 9; k++) {
        float dy = om_bias[2 * k];
        float dx = om_bias[2 * k + 1];
        float mm = om_bias[18 + k];
#pragma unroll
        for (int q = 0; q < 4; q++) {
            const float* p = omp + ((q * 8 + b) * 27) * 4096 + hw;
            dy += p[(2 * k) * 4096];
            dx += p[(2 * k + 1) * 4096];
            mm += p[(18 + k) * 4096];
        }
        mm = 1.f / (1.f + __expf(-mm));   // sigmoid(mask)
        float yy = (float)(h - 1 + k / 3) + dy;
        float xx = (float)(w - 1 + (k - (k / 3) * 3)) + dx;
        float fy = floorf(yy), fx = floorf(xx);
        int y0 = (int)fy, x0 = (int)fx;
        float wy = yy - fy, wx = xx - fx;
        bool vy0 = (y0 >= 0) & (y0 < 64);
        bool vy1 = (y0 >= -1) & (y0 < 63);
        bool vx0 = (x0 >= 0) & (x0 < 64);
        bool vx1 = (x0 >= -1) & (x0 < 63);
        float a0 = (1.f - wy) * mm, a1 = wy * mm;
        W00[k] = a0 * (1.f - wx) * (float)(vy0 & vx0);
        W01[k] = a0 * wx         * (float)(vy0 & vx1);
        W10[k] = a1 * (1.f - wx) * (float)(vy1 & vx0);
        W11[k] = a1 * wx         * (float)(vy1 & vx1);
        // Each tap index is clamped INDEPENDENTLY (y0+1 clamped, not
        // clamp(y0)+1): for y0==-1 the y1 tap is row 0 and VALID.
        int iy0 = min(max(y0, 0), 63),     ix0 = min(max(x0, 0), 63);
        int iy1 = min(max(y0 + 1, 0), 63), ix1 = min(max(x0 + 1, 0), 63);
        A00[k] = iy0 * 64 + ix0;  A01[k] = iy0 * 64 + ix1;
        A10[k] = iy1 * 64 + ix0;  A11[k] = iy1 * 64 + ix1;
    }

    float acc[64];
#pragma unroll
    for (int o = 0; o < 64; o++) acc[o] = 0.f;

    for (int ci = 0; ci < 16; ci++) {
        const int c = wv * 16 + ci;   // scalar (wv from readfirstlane)
        const float* sp = feat + (b * 64 + c) * 4096;
        float s[9];
#pragma unroll
        for (int k = 0; k < 9; k++) {
            s[k] = W00[k] * sp[A00[k]] + W01[k] * sp[A01[k]]
                 + W10[k] * sp[A10[k]] + W11[k] * sp[A11[k]];
        }
        const float* wc = Wt + c * 576;   // uniform -> s_load
#pragma unroll
        for (int o = 0; o < 64; o++) {
            float a = acc[o];
#pragma unroll
            for (int k = 0; k < 9; k++)
                a = fmaf(s[k], wc[k * 64 + o], a);
            acc[o] = a;
        }
    }

    // reduce the 4 wave partials (lane = w, 64 o's) through LDS
    for (int r = 0; r < 4; r++) {
        if (wv == r) {
            if (r == 0) {
#pragma unroll
                for (int o = 0; o < 64; o++) red[o * 64 + w] = acc[o];
            } else {
#pragma unroll
                for (int o = 0; o < 64; o++) red[o * 64 + w] += acc[o];
            }
        }
        __syncthreads();
    }

    float* ob = out + (b * 64) * 4096 + h * 64;
#pragma unroll
    for (int j = 0; j < 16; j++) {
        int idx = j * 256 + threadIdx.x;
        int o = idx >> 6, ww = idx & 63;
        ob[o * 4096 + ww] = red[idx];
    }
}

extern "C" void kernel_launch(void* const* d_in, const int* in_sizes, int n_in,
                              void* d_out, int out_size, void* d_ws, size_t ws_size,
                              hipStream_t stream)
{
    const float* feat      = (const float*)d_in[0];
    const float* deg       = (const float*)d_in[1];
    const float* weight    = (const float*)d_in[2];
    const float* om_weight = (const float*)d_in[3];
    const float* om_bias   = (const float*)d_in[4];
    float* out = (float*)d_out;
    float* ws  = (float*)d_ws;

    hipLaunchKernelGGL(prep_kernel,   dim3(266), dim3(256), 0, stream,
                       weight, om_weight, ws);
    hipLaunchKernelGGL(omconv_kernel, dim3(512), dim3(256), 0, stream,
                       feat, deg, ws, ws + OMP_OFF);
    hipLaunchKernelGGL(deform_kernel, dim3(512), dim3(256), 0, stream,
                       feat, om_bias, ws, out);
}